// Round 1
// baseline (1063.920 us; speedup 1.0000x reference)
//
#include <hip/hip_runtime.h>

#define NTOK 8192
#define CDIM 1024
#define ENUM 8
#define HDIM 4096

typedef unsigned short u16;
typedef unsigned int u32;
typedef __attribute__((ext_vector_type(8))) short s16x8;
typedef __attribute__((ext_vector_type(4))) float f32x4;

static __device__ __forceinline__ u16 f2bf(float f) {
  union { float f; u32 u; } v; v.f = f;
  u32 r = v.u + 0x7fffu + ((v.u >> 16) & 1u);
  return (u16)(r >> 16);
}
static __device__ __forceinline__ u32 pack2(float a, float b) {
  return (u32)f2bf(a) | ((u32)f2bf(b) << 16);
}

// ---------------- gating: logits = x @ w_gate, top-2, softmax ----------------
__global__ void gate_kernel(const float* __restrict__ x, const float* __restrict__ wg,
                            int* __restrict__ cnt, int* __restrict__ tok_e,
                            float* __restrict__ tok_w) {
  int gw = (blockIdx.x * blockDim.x + threadIdx.x) >> 6;  // one wave per token
  int lane = threadIdx.x & 63;
  if (gw >= NTOK) return;
  const float* xr = x + (size_t)gw * CDIM;
  float acc[ENUM];
#pragma unroll
  for (int e = 0; e < ENUM; ++e) acc[e] = 0.f;
  for (int i = 0; i < CDIM / 64; ++i) {
    int c = i * 64 + lane;
    float xv = xr[c];
    float4 wa = *(const float4*)(wg + (size_t)c * ENUM);
    float4 wb = *(const float4*)(wg + (size_t)c * ENUM + 4);
    acc[0] += xv * wa.x; acc[1] += xv * wa.y; acc[2] += xv * wa.z; acc[3] += xv * wa.w;
    acc[4] += xv * wb.x; acc[5] += xv * wb.y; acc[6] += xv * wb.z; acc[7] += xv * wb.w;
  }
#pragma unroll
  for (int e = 0; e < ENUM; ++e) {
#pragma unroll
    for (int off = 32; off > 0; off >>= 1) acc[e] += __shfl_xor(acc[e], off);
  }
  if (lane == 0) {
    int i0 = 0; float v0 = acc[0];
#pragma unroll
    for (int e = 1; e < ENUM; ++e) if (acc[e] > v0) { v0 = acc[e]; i0 = e; }
    int i1 = -1; float v1 = -3.4e38f;
#pragma unroll
    for (int e = 0; e < ENUM; ++e) if (e != i0 && acc[e] > v1) { v1 = acc[e]; i1 = e; }
    float ex = expf(v1 - v0);         // softmax over the top-2 (max-shifted)
    float den = 1.f + ex;
    tok_e[gw * 2] = i0;     tok_w[gw * 2] = 1.f / den;
    tok_e[gw * 2 + 1] = i1; tok_w[gw * 2 + 1] = ex / den;
    atomicAdd(&cnt[i0], 1); atomicAdd(&cnt[i1], 1);
  }
}

__global__ void offsets_kernel(const int* __restrict__ cnt, int* __restrict__ offs) {
  if (threadIdx.x == 0 && blockIdx.x == 0) {
    int s = 0;
    for (int e = 0; e < ENUM; ++e) { offs[e] = s; s += cnt[e]; }
  }
}

__global__ void assign_kernel(const int* __restrict__ tok_e, const float* __restrict__ tok_w,
                              const int* __restrict__ offs, int* __restrict__ fill,
                              int* __restrict__ slot_tok, float* __restrict__ slot_w) {
  int n = blockIdx.x * blockDim.x + threadIdx.x;
  if (n >= NTOK) return;
#pragma unroll
  for (int j = 0; j < 2; ++j) {
    int e = tok_e[n * 2 + j];
    int pos = atomicAdd(&fill[e], 1);
    int slot = offs[e] + pos;
    slot_tok[slot] = n;
    slot_w[slot] = tok_w[n * 2 + j];
  }
}

// gather routed rows of x into packed bf16 matrix xg [2N][C]
__global__ void gather_kernel(const float* __restrict__ x, const int* __restrict__ slot_tok,
                              u16* __restrict__ xg) {
  int gid = blockIdx.x * blockDim.x + threadIdx.x;  // 16384*256 threads
  int slot = gid >> 8;
  int c4 = (gid & 255) * 4;
  int tok = slot_tok[slot];
  float4 v = *(const float4*)(x + (size_t)tok * CDIM + c4);
  uint2 o; o.x = pack2(v.x, v.y); o.y = pack2(v.z, v.w);
  *(uint2*)(xg + (size_t)slot * CDIM + c4) = o;
}

// ---------------- expert GEMMs ----------------
// PHASE 1: h = gelu(xg @ w1[e] + b1[e])   (A bf16 [slots][K=1024], B f32 [K][4096])
// PHASE 2: out[tok] += w * (h @ w2[e] + b2[e])  (A bf16 [slots][K=4096], B f32 [K][1024])
// 128x128 tile, BK=64, 4 waves (2x2), 16x16x32 bf16 MFMA.
// LDS: A and B^T both stored as [128 rows][8 k-octets], 16B units XOR-swizzled by (row&7).
template <int PHASE>
__global__ __launch_bounds__(256, 2) void moe_gemm(
    const u16* __restrict__ Ag, const float* __restrict__ Bw, const float* __restrict__ bias,
    u16* __restrict__ h_out, float* __restrict__ out,
    const int* __restrict__ cnts, const int* __restrict__ offs,
    const int* __restrict__ slot_tok, const float* __restrict__ slot_w,
    int K, int Nn) {
  const int e = blockIdx.z;
  const int cnt = cnts[e];
  const int mt = blockIdx.y;
  if (mt * 128 >= cnt) return;
  const int nt = blockIdx.x;
  const int moff = offs[e];
  const int tid = threadIdx.x;

  __shared__ __align__(16) u16 lA[128 * 64];
  __shared__ __align__(16) u16 lB[128 * 64];

  const int a_ko = tid & 7;   // k-octet (8 bf16 = 16B)
  const int a_r0 = tid >> 3;  // row 0..31 (+32*i)
  const int b_kb = tid & 7;   // k-octet
  const int b_nb = tid >> 3;  // n-quad 0..31

  const size_t bbase = (size_t)e * K * Nn + (size_t)nt * 128;

  uint4 aR[4];
  uint4 bR[4];

  auto LOAD = [&](int kt) {
#pragma unroll
    for (int i = 0; i < 4; ++i) {
      int row = a_r0 + 32 * i;
      int grow = mt * 128 + row;
      if (grow < cnt) {
        aR[i] = *(const uint4*)(Ag + (size_t)(moff + grow) * K + kt * 64 + a_ko * 8);
      } else {
        aR[i] = make_uint4(0u, 0u, 0u, 0u);
      }
    }
    float4 t[8];
#pragma unroll
    for (int j = 0; j < 8; ++j)
      t[j] = *(const float4*)(Bw + bbase + (size_t)(kt * 64 + b_kb * 8 + j) * Nn + b_nb * 4);
#pragma unroll
    for (int i = 0; i < 4; ++i) {
      uint4 p;
      p.x = pack2(((const float*)&t[0])[i], ((const float*)&t[1])[i]);
      p.y = pack2(((const float*)&t[2])[i], ((const float*)&t[3])[i]);
      p.z = pack2(((const float*)&t[4])[i], ((const float*)&t[5])[i]);
      p.w = pack2(((const float*)&t[6])[i], ((const float*)&t[7])[i]);
      bR[i] = p;
    }
  };

  auto STORE_LDS = [&]() {
#pragma unroll
    for (int i = 0; i < 4; ++i) {
      int row = a_r0 + 32 * i;
      ((uint4*)lA)[row * 8 + (a_ko ^ (row & 7))] = aR[i];
    }
#pragma unroll
    for (int i = 0; i < 4; ++i) {
      int nl = b_nb * 4 + i;
      ((uint4*)lB)[nl * 8 + (b_kb ^ (nl & 7))] = bR[i];
    }
  };

  const int w = tid >> 6;
  const int wm = w >> 1, wn = w & 1;
  const int l = tid & 63;
  const int lr = l & 15;
  const int lg = l >> 4;

  f32x4 acc[4][4];
#pragma unroll
  for (int m = 0; m < 4; ++m)
#pragma unroll
    for (int n = 0; n < 4; ++n) {
      acc[m][n][0] = 0.f; acc[m][n][1] = 0.f; acc[m][n][2] = 0.f; acc[m][n][3] = 0.f;
    }

  const int nk = K / 64;
  LOAD(0);
  for (int kt = 0; kt < nk; ++kt) {
    __syncthreads();   // previous tile's ds_reads done
    STORE_LDS();
    if (kt + 1 < nk) LOAD(kt + 1);  // prefetch stays in flight across compute
    __syncthreads();
#pragma unroll
    for (int ko = 0; ko < 2; ++ko) {
      s16x8 af[4], bf[4];
#pragma unroll
      for (int m = 0; m < 4; ++m) {
        int row = wm * 64 + m * 16 + lr;
        af[m] = ((const s16x8*)lA)[row * 8 + ((ko * 4 + lg) ^ (lr & 7))];
      }
#pragma unroll
      for (int n = 0; n < 4; ++n) {
        int col = wn * 64 + n * 16 + lr;
        bf[n] = ((const s16x8*)lB)[col * 8 + ((ko * 4 + lg) ^ (lr & 7))];
      }
#pragma unroll
      for (int m = 0; m < 4; ++m)
#pragma unroll
        for (int n = 0; n < 4; ++n)
          acc[m][n] = __builtin_amdgcn_mfma_f32_16x16x32_bf16(af[m], bf[n], acc[m][n], 0, 0, 0);
    }
  }

  // epilogue
  const int gcol0 = nt * 128 + wn * 64;
  float bv[4];
#pragma unroll
  for (int n = 0; n < 4; ++n) bv[n] = bias[(size_t)e * Nn + gcol0 + n * 16 + lr];
#pragma unroll
  for (int m = 0; m < 4; ++m) {
#pragma unroll
    for (int r = 0; r < 4; ++r) {
      int rowl = wm * 64 + m * 16 + lg * 4 + r;
      int grow = mt * 128 + rowl;
      if (grow < cnt) {
        int gslot = moff + grow;
        if (PHASE == 1) {
#pragma unroll
          for (int n = 0; n < 4; ++n) {
            int gcol = gcol0 + n * 16 + lr;
            float v = acc[m][n][r] + bv[n];
            v = 0.5f * v * (1.f + erff(v * 0.70710678118654752f));  // exact gelu
            h_out[(size_t)gslot * Nn + gcol] = f2bf(v);
          }
        } else {
          float wgt = slot_w[gslot];
          int tok = slot_tok[gslot];
#pragma unroll
          for (int n = 0; n < 4; ++n) {
            int gcol = gcol0 + n * 16 + lr;
            float v = acc[m][n][r] + bv[n];
            atomicAdd(&out[(size_t)tok * CDIM + gcol], wgt * v);
          }
        }
      }
    }
  }
}

extern "C" void kernel_launch(void* const* d_in, const int* in_sizes, int n_in,
                              void* d_out, int out_size, void* d_ws, size_t ws_size,
                              hipStream_t stream) {
  const float* x  = (const float*)d_in[0];
  const float* wg = (const float*)d_in[1];
  const float* w1 = (const float*)d_in[2];
  const float* b1 = (const float*)d_in[3];
  const float* w2 = (const float*)d_in[4];
  const float* b2 = (const float*)d_in[5];
  float* out = (float*)d_out;

  char* ws = (char*)d_ws;
  int* cnt  = (int*)ws;        // 8 ints
  int* fill = cnt + 8;         // 8 ints
  int* offs = cnt + 16;        // 8 ints
  size_t off = 256;
  int*   tok_e    = (int*)(ws + off);   off += (size_t)NTOK * 2 * 4;
  float* tok_w    = (float*)(ws + off); off += (size_t)NTOK * 2 * 4;
  int*   slot_tok = (int*)(ws + off);   off += (size_t)NTOK * 2 * 4;
  float* slot_w   = (float*)(ws + off); off += (size_t)NTOK * 2 * 4;
  u16*   xg       = (u16*)(ws + off);   off += (size_t)NTOK * 2 * CDIM * 2;  // 33.5 MB
  u16*   h        = (u16*)(ws + off);   off += (size_t)NTOK * 2 * HDIM * 2;  // 134 MB

  hipMemsetAsync(d_out, 0, (size_t)NTOK * CDIM * 4, stream);
  hipMemsetAsync(cnt, 0, 64, stream);  // cnt + fill

  gate_kernel<<<NTOK / 4, 256, 0, stream>>>(x, wg, cnt, tok_e, tok_w);
  offsets_kernel<<<1, 64, 0, stream>>>(cnt, offs);
  assign_kernel<<<NTOK / 256, 256, 0, stream>>>(tok_e, tok_w, offs, fill, slot_tok, slot_w);
  gather_kernel<<<NTOK * 2, 256, 0, stream>>>(x, slot_tok, xg);

  moe_gemm<1><<<dim3(HDIM / 128, NTOK / 128, ENUM), 256, 0, stream>>>(
      xg, w1, b1, h, nullptr, cnt, offs, slot_tok, slot_w, CDIM, HDIM);
  moe_gemm<2><<<dim3(CDIM / 128, NTOK / 128, ENUM), 256, 0, stream>>>(
      h, w2, b2, nullptr, out, cnt, offs, slot_tok, slot_w, HDIM, CDIM);
}

// Round 2
// 876.412 us; speedup vs baseline: 1.2139x; 1.2139x over previous
//
#include <hip/hip_runtime.h>

#define NTOK 8192
#define CDIM 1024
#define ENUM 8
#define HDIM 4096

typedef unsigned short u16;
typedef unsigned int u32;
typedef __attribute__((ext_vector_type(8))) short s16x8;
typedef __attribute__((ext_vector_type(4))) float f32x4;

static __device__ __forceinline__ u16 f2bf(float f) {
  union { float f; u32 u; } v; v.f = f;
  u32 r = v.u + 0x7fffu + ((v.u >> 16) & 1u);
  return (u16)(r >> 16);
}
static __device__ __forceinline__ u32 pack2(float a, float b) {
  return (u32)f2bf(a) | ((u32)f2bf(b) << 16);
}

typedef __attribute__((address_space(1))) const void gvoid;
typedef __attribute__((address_space(3))) void lvoid;
static __device__ __forceinline__ void gload16(const u16* g, u16* l) {
  __builtin_amdgcn_global_load_lds((gvoid*)g, (lvoid*)l, 16, 0, 0);
}

// ---------------- weight convert + transpose: w[E][K][N] f32 -> wt[E][N][K] bf16 ----
__global__ void wconv_kernel(const float* __restrict__ w, u16* __restrict__ wt,
                             int K, int N) {
  __shared__ float lt[64][65];
  const int e = blockIdx.z, k0 = blockIdx.y * 64, n0 = blockIdx.x * 64;
  const float* src = w + (size_t)e * K * N;
  u16* dst = wt + (size_t)e * N * K;
  const int t = threadIdx.x;
  const int tr = t >> 4, tc = (t & 15) * 4;
#pragma unroll
  for (int i = 0; i < 4; ++i) {
    float4 v = *(const float4*)(src + (size_t)(k0 + tr + i * 16) * N + n0 + tc);
    lt[tr + i * 16][tc] = v.x; lt[tr + i * 16][tc + 1] = v.y;
    lt[tr + i * 16][tc + 2] = v.z; lt[tr + i * 16][tc + 3] = v.w;
  }
  __syncthreads();
#pragma unroll
  for (int i = 0; i < 4; ++i) {
    int n = tr + i * 16;
    uint2 o;
    o.x = pack2(lt[tc + 0][n], lt[tc + 1][n]);
    o.y = pack2(lt[tc + 2][n], lt[tc + 3][n]);
    *(uint2*)(dst + (size_t)(n0 + n) * K + k0 + tc) = o;
  }
}

// ---------------- gating: logits = x @ w_gate, top-2, softmax ----------------
__global__ void gate_kernel(const float* __restrict__ x, const float* __restrict__ wg,
                            int* __restrict__ cnt, int* __restrict__ tok_e,
                            float* __restrict__ tok_w) {
  int gw = (blockIdx.x * blockDim.x + threadIdx.x) >> 6;  // one wave per token
  int lane = threadIdx.x & 63;
  if (gw >= NTOK) return;
  const float* xr = x + (size_t)gw * CDIM;
  float acc[ENUM];
#pragma unroll
  for (int e = 0; e < ENUM; ++e) acc[e] = 0.f;
  for (int i = 0; i < CDIM / 64; ++i) {
    int c = i * 64 + lane;
    float xv = xr[c];
    float4 wa = *(const float4*)(wg + (size_t)c * ENUM);
    float4 wb = *(const float4*)(wg + (size_t)c * ENUM + 4);
    acc[0] += xv * wa.x; acc[1] += xv * wa.y; acc[2] += xv * wa.z; acc[3] += xv * wa.w;
    acc[4] += xv * wb.x; acc[5] += xv * wb.y; acc[6] += xv * wb.z; acc[7] += xv * wb.w;
  }
#pragma unroll
  for (int e = 0; e < ENUM; ++e) {
#pragma unroll
    for (int off = 32; off > 0; off >>= 1) acc[e] += __shfl_xor(acc[e], off);
  }
  if (lane == 0) {
    int i0 = 0; float v0 = acc[0];
#pragma unroll
    for (int e = 1; e < ENUM; ++e) if (acc[e] > v0) { v0 = acc[e]; i0 = e; }
    int i1 = -1; float v1 = -3.4e38f;
#pragma unroll
    for (int e = 0; e < ENUM; ++e) if (e != i0 && acc[e] > v1) { v1 = acc[e]; i1 = e; }
    float ex = expf(v1 - v0);
    float den = 1.f + ex;
    tok_e[gw * 2] = i0;     tok_w[gw * 2] = 1.f / den;
    tok_e[gw * 2 + 1] = i1; tok_w[gw * 2 + 1] = ex / den;
    atomicAdd(&cnt[i0], 1); atomicAdd(&cnt[i1], 1);
  }
}

__global__ void offsets_kernel(const int* __restrict__ cnt, int* __restrict__ offs) {
  if (threadIdx.x == 0 && blockIdx.x == 0) {
    int s = 0;
    for (int e = 0; e < ENUM; ++e) { offs[e] = s; s += cnt[e]; }
  }
}

__global__ void assign_kernel(const int* __restrict__ tok_e, const float* __restrict__ tok_w,
                              const int* __restrict__ offs, int* __restrict__ fill,
                              int* __restrict__ slot_tok, float* __restrict__ slot_w) {
  int n = blockIdx.x * blockDim.x + threadIdx.x;
  if (n >= NTOK) return;
#pragma unroll
  for (int j = 0; j < 2; ++j) {
    int e = tok_e[n * 2 + j];
    int pos = atomicAdd(&fill[e], 1);
    int slot = offs[e] + pos;
    slot_tok[slot] = n;
    slot_w[slot] = tok_w[n * 2 + j];
  }
}

// gather routed rows of x into packed bf16 matrix xg [2N][C]
__global__ void gather_kernel(const float* __restrict__ x, const int* __restrict__ slot_tok,
                              u16* __restrict__ xg) {
  int gid = blockIdx.x * blockDim.x + threadIdx.x;
  int slot = gid >> 8;
  int c4 = (gid & 255) * 4;
  int tok = slot_tok[slot];
  float4 v = *(const float4*)(x + (size_t)tok * CDIM + c4);
  uint2 o; o.x = pack2(v.x, v.y); o.y = pack2(v.z, v.w);
  *(uint2*)(xg + (size_t)slot * CDIM + c4) = o;
}

// ---------------- expert GEMMs (m97 structure) ----------------
// A  : bf16 [slots][K] row-major
// B^T: bf16 [E][N][K] row-major (pre-transposed weights)
// 128x128 tile, BK=64, 4 waves (2x2), 16x16x32 bf16 MFMA, global_load_lds staging.
template <int PHASE>
__global__ __launch_bounds__(256, 2) void moe_gemm(
    const u16* __restrict__ Ag, const u16* __restrict__ Bt, const float* __restrict__ bias,
    u16* __restrict__ h_out, float* __restrict__ out,
    const int* __restrict__ cnts, const int* __restrict__ offs,
    const int* __restrict__ slot_tok, const float* __restrict__ slot_w,
    int K, int Nn) {
  const int e = blockIdx.z;
  const int cnt = cnts[e];
  const int mt = blockIdx.y;
  if (mt * 128 >= cnt) return;
  const int nt = blockIdx.x;
  const int moff = offs[e];
  const int tid = threadIdx.x;
  const int wv = tid >> 6, ln = tid & 63;
  const int lr = ln & 15, lg = ln >> 4;
  const int wm = wv >> 1, wn = wv & 1;

  __shared__ __align__(16) u16 lA[128 * 64];
  __shared__ __align__(16) u16 lB[128 * 64];

  const u16* Abase = Ag + (size_t)moff * K;
  const u16* Bbase = Bt + (size_t)e * Nn * K + (size_t)nt * 128 * K;

  const int srow = ln >> 3;        // row-in-chunk 0..7
  const int sk = (ln & 7) * 8;     // k element offset

  f32x4 acc[4][4];
#pragma unroll
  for (int m = 0; m < 4; ++m)
#pragma unroll
    for (int n = 0; n < 4; ++n) {
      acc[m][n][0] = 0.f; acc[m][n][1] = 0.f; acc[m][n][2] = 0.f; acc[m][n][3] = 0.f;
    }

  const int nk = K / 64;
  for (int kt = 0; kt < nk; ++kt) {
    // stage tile kt: 16 chunks of 8 rows each for A and B (4 per wave)
#pragma unroll
    for (int i = 0; i < 4; ++i) {
      int c = wv * 4 + i;
      int ra = mt * 128 + c * 8 + srow;
      ra = ra < cnt ? ra : cnt - 1;  // clamp: padded rows discarded in epilogue
      gload16(Abase + (size_t)ra * K + kt * 64 + sk, lA + c * 512);
      gload16(Bbase + (size_t)(c * 8 + srow) * K + kt * 64 + sk, lB + c * 512);
    }
    __syncthreads();  // compiler drains vmcnt before barrier -> LDS tile ready
#pragma unroll
    for (int ko = 0; ko < 2; ++ko) {
      s16x8 af[4], bfr[4];
#pragma unroll
      for (int m = 0; m < 4; ++m)
        af[m] = *(const s16x8*)(lA + (wm * 64 + m * 16 + lr) * 64 + ko * 32 + lg * 8);
#pragma unroll
      for (int n = 0; n < 4; ++n)
        bfr[n] = *(const s16x8*)(lB + (wn * 64 + n * 16 + lr) * 64 + ko * 32 + lg * 8);
#pragma unroll
      for (int m = 0; m < 4; ++m)
#pragma unroll
        for (int n = 0; n < 4; ++n)
          acc[m][n] = __builtin_amdgcn_mfma_f32_16x16x32_bf16(af[m], bfr[n], acc[m][n], 0, 0, 0);
    }
    __syncthreads();  // LDS free before next stage
  }

  // epilogue
  const int gcol0 = nt * 128 + wn * 64;
  float bv[4];
#pragma unroll
  for (int n = 0; n < 4; ++n) bv[n] = bias[(size_t)e * Nn + gcol0 + n * 16 + lr];
#pragma unroll
  for (int m = 0; m < 4; ++m) {
#pragma unroll
    for (int r = 0; r < 4; ++r) {
      int rowl = wm * 64 + m * 16 + lg * 4 + r;
      int grow = mt * 128 + rowl;
      if (grow < cnt) {
        int gslot = moff + grow;
        if (PHASE == 1) {
#pragma unroll
          for (int n = 0; n < 4; ++n) {
            int gcol = gcol0 + n * 16 + lr;
            float v = acc[m][n][r] + bv[n];
            v = 0.5f * v * (1.f + erff(v * 0.70710678118654752f));  // exact gelu
            h_out[(size_t)gslot * Nn + gcol] = f2bf(v);
          }
        } else {
          float wgt = slot_w[gslot];
          int tok = slot_tok[gslot];
#pragma unroll
          for (int n = 0; n < 4; ++n) {
            int gcol = gcol0 + n * 16 + lr;
            float v = acc[m][n][r] + bv[n];
            atomicAdd(&out[(size_t)tok * CDIM + gcol], wgt * v);
          }
        }
      }
    }
  }
}

extern "C" void kernel_launch(void* const* d_in, const int* in_sizes, int n_in,
                              void* d_out, int out_size, void* d_ws, size_t ws_size,
                              hipStream_t stream) {
  const float* x  = (const float*)d_in[0];
  const float* wg = (const float*)d_in[1];
  const float* w1 = (const float*)d_in[2];
  const float* b1 = (const float*)d_in[3];
  const float* w2 = (const float*)d_in[4];
  const float* b2 = (const float*)d_in[5];
  float* out = (float*)d_out;

  char* ws = (char*)d_ws;
  int* cnt  = (int*)ws;        // 8 ints
  int* fill = cnt + 8;         // 8 ints
  int* offs = cnt + 16;        // 8 ints
  size_t off = 256;
  int*   tok_e    = (int*)(ws + off);   off += (size_t)NTOK * 2 * 4;
  float* tok_w    = (float*)(ws + off); off += (size_t)NTOK * 2 * 4;
  int*   slot_tok = (int*)(ws + off);   off += (size_t)NTOK * 2 * 4;
  float* slot_w   = (float*)(ws + off); off += (size_t)NTOK * 2 * 4;
  u16*   xg  = (u16*)(ws + off); off += (size_t)NTOK * 2 * CDIM * 2;        // 33.5 MB
  u16*   h   = (u16*)(ws + off); off += (size_t)NTOK * 2 * HDIM * 2;        // 134 MB
  u16*   w1t = (u16*)(ws + off); off += (size_t)ENUM * CDIM * HDIM * 2;     // 67 MB
  u16*   w2t = (u16*)(ws + off); off += (size_t)ENUM * HDIM * CDIM * 2;     // 67 MB

  hipMemsetAsync(d_out, 0, (size_t)NTOK * CDIM * 4, stream);
  hipMemsetAsync(cnt, 0, 64, stream);  // cnt + fill

  // weights: f32 [E][K][N] -> bf16 [E][N][K]
  wconv_kernel<<<dim3(HDIM / 64, CDIM / 64, ENUM), 256, 0, stream>>>(w1, w1t, CDIM, HDIM);
  wconv_kernel<<<dim3(CDIM / 64, HDIM / 64, ENUM), 256, 0, stream>>>(w2, w2t, HDIM, CDIM);

  gate_kernel<<<NTOK / 4, 256, 0, stream>>>(x, wg, cnt, tok_e, tok_w);
  offsets_kernel<<<1, 64, 0, stream>>>(cnt, offs);
  assign_kernel<<<NTOK / 256, 256, 0, stream>>>(tok_e, tok_w, offs, fill, slot_tok, slot_w);
  gather_kernel<<<NTOK * 2, 256, 0, stream>>>(x, slot_tok, xg);

  moe_gemm<1><<<dim3(HDIM / 128, NTOK / 128, ENUM), 256, 0, stream>>>(
      xg, w1t, b1, h, nullptr, cnt, offs, slot_tok, slot_w, CDIM, HDIM);
  moe_gemm<2><<<dim3(CDIM / 128, NTOK / 128, ENUM), 256, 0, stream>>>(
      h, w2t, b2, nullptr, out, cnt, offs, slot_tok, slot_w, HDIM, CDIM);
}

// Round 3
// 763.407 us; speedup vs baseline: 1.3936x; 1.1480x over previous
//
#include <hip/hip_runtime.h>

#define NTOK 8192
#define CDIM 1024
#define ENUM 8
#define HDIM 4096

typedef unsigned short u16;
typedef unsigned int u32;
typedef __attribute__((ext_vector_type(8))) short s16x8;
typedef __attribute__((ext_vector_type(4))) float f32x4;

static __device__ __forceinline__ u16 f2bf(float f) {
  union { float f; u32 u; } v; v.f = f;
  u32 r = v.u + 0x7fffu + ((v.u >> 16) & 1u);
  return (u16)(r >> 16);
}
static __device__ __forceinline__ u32 pack2(float a, float b) {
  return (u32)f2bf(a) | ((u32)f2bf(b) << 16);
}
static __device__ __forceinline__ float bflo(u32 v) {
  union { u32 u; float f; } x; x.u = v << 16; return x.f;
}
static __device__ __forceinline__ float bfhi(u32 v) {
  union { u32 u; float f; } x; x.u = v & 0xffff0000u; return x.f;
}

typedef __attribute__((address_space(1))) const void gvoid;
typedef __attribute__((address_space(3))) void lvoid;
static __device__ __forceinline__ void gload16(const u16* g, u16* l) {
  __builtin_amdgcn_global_load_lds((gvoid*)g, (lvoid*)l, 16, 0, 0);
}

// gelu(x) ~= x * sigmoid(2*0.79788456*(x + 0.044715 x^3)); max dev ~1e-3 vs erf form
static __device__ __forceinline__ float gelu_fast(float v) {
  float u = v * (1.5957691216f + 0.1426929792f * v * v);  // 2*c0*(v + 0.044715 v^3)
  return v / (1.f + __expf(-u));
}

// ---------------- weight convert + transpose: w[E][K][N] f32 -> wt[E][N][K] bf16 ----
__global__ void wconv_kernel(const float* __restrict__ w, u16* __restrict__ wt,
                             int K, int N) {
  __shared__ float lt[64][65];
  const int e = blockIdx.z, k0 = blockIdx.y * 64, n0 = blockIdx.x * 64;
  const float* src = w + (size_t)e * K * N;
  u16* dst = wt + (size_t)e * N * K;
  const int t = threadIdx.x;
  const int tr = t >> 4, tc = (t & 15) * 4;
#pragma unroll
  for (int i = 0; i < 4; ++i) {
    float4 v = *(const float4*)(src + (size_t)(k0 + tr + i * 16) * N + n0 + tc);
    lt[tr + i * 16][tc] = v.x; lt[tr + i * 16][tc + 1] = v.y;
    lt[tr + i * 16][tc + 2] = v.z; lt[tr + i * 16][tc + 3] = v.w;
  }
  __syncthreads();
#pragma unroll
  for (int i = 0; i < 4; ++i) {
    int n = tr + i * 16;
    uint2 o;
    o.x = pack2(lt[tc + 0][n], lt[tc + 1][n]);
    o.y = pack2(lt[tc + 2][n], lt[tc + 3][n]);
    *(uint2*)(dst + (size_t)(n0 + n) * K + k0 + tc) = o;
  }
}

// ---------------- gating ----------------
__global__ void gate_kernel(const float* __restrict__ x, const float* __restrict__ wg,
                            int* __restrict__ cnt, int* __restrict__ tok_e,
                            float* __restrict__ tok_w) {
  int gw = (blockIdx.x * blockDim.x + threadIdx.x) >> 6;
  int lane = threadIdx.x & 63;
  if (gw >= NTOK) return;
  const float* xr = x + (size_t)gw * CDIM;
  float acc[ENUM];
#pragma unroll
  for (int e = 0; e < ENUM; ++e) acc[e] = 0.f;
  for (int i = 0; i < CDIM / 64; ++i) {
    int c = i * 64 + lane;
    float xv = xr[c];
    float4 wa = *(const float4*)(wg + (size_t)c * ENUM);
    float4 wb = *(const float4*)(wg + (size_t)c * ENUM + 4);
    acc[0] += xv * wa.x; acc[1] += xv * wa.y; acc[2] += xv * wa.z; acc[3] += xv * wa.w;
    acc[4] += xv * wb.x; acc[5] += xv * wb.y; acc[6] += xv * wb.z; acc[7] += xv * wb.w;
  }
#pragma unroll
  for (int e = 0; e < ENUM; ++e) {
#pragma unroll
    for (int off = 32; off > 0; off >>= 1) acc[e] += __shfl_xor(acc[e], off);
  }
  if (lane == 0) {
    int i0 = 0; float v0 = acc[0];
#pragma unroll
    for (int e = 1; e < ENUM; ++e) if (acc[e] > v0) { v0 = acc[e]; i0 = e; }
    int i1 = -1; float v1 = -3.4e38f;
#pragma unroll
    for (int e = 0; e < ENUM; ++e) if (e != i0 && acc[e] > v1) { v1 = acc[e]; i1 = e; }
    float ex = expf(v1 - v0);
    float den = 1.f + ex;
    tok_e[gw * 2] = i0;     tok_w[gw * 2] = 1.f / den;
    tok_e[gw * 2 + 1] = i1; tok_w[gw * 2 + 1] = ex / den;
    atomicAdd(&cnt[i0], 1); atomicAdd(&cnt[i1], 1);
  }
}

__global__ void offsets_kernel(const int* __restrict__ cnt, int* __restrict__ offs) {
  if (threadIdx.x == 0 && blockIdx.x == 0) {
    int s = 0;
    for (int e = 0; e < ENUM; ++e) { offs[e] = s; s += cnt[e]; }
  }
}

__global__ void assign_kernel(const int* __restrict__ tok_e, const int* __restrict__ offs,
                              int* __restrict__ fill, int* __restrict__ slot_tok,
                              int* __restrict__ tok_slot) {
  int n = blockIdx.x * blockDim.x + threadIdx.x;
  if (n >= NTOK) return;
#pragma unroll
  for (int j = 0; j < 2; ++j) {
    int e = tok_e[n * 2 + j];
    int pos = atomicAdd(&fill[e], 1);
    int slot = offs[e] + pos;
    slot_tok[slot] = n;
    tok_slot[n * 2 + j] = slot;
  }
}

// gather routed rows of x into packed bf16 matrix xg [2N][C]
__global__ void gather_kernel(const float* __restrict__ x, const int* __restrict__ slot_tok,
                              u16* __restrict__ xg) {
  int gid = blockIdx.x * blockDim.x + threadIdx.x;
  int slot = gid >> 8;
  int c4 = (gid & 255) * 4;
  int tok = slot_tok[slot];
  float4 v = *(const float4*)(x + (size_t)tok * CDIM + c4);
  uint2 o; o.x = pack2(v.x, v.y); o.y = pack2(v.z, v.w);
  *(uint2*)(xg + (size_t)slot * CDIM + c4) = o;
}

// ---------------- expert GEMMs ----------------
// A: bf16 [slots][K]; B^T: bf16 [E][N][K]. 128x128 tile, BK=64, 4 waves, 16x16x32 MFMA.
// LDS linear (global_load_lds) with SOURCE-side XOR octet swizzle; reads XOR back.
// PHASE 1: h = gelu_fast(A @ B + b1)  (bf16 out)
// PHASE 2: y = A @ B + b2             (bf16 out, unweighted; combined later)
template <int PHASE>
__global__ __launch_bounds__(256, 2) void moe_gemm(
    const u16* __restrict__ Ag, const u16* __restrict__ Bt, const float* __restrict__ bias,
    u16* __restrict__ outp,
    const int* __restrict__ cnts, const int* __restrict__ offs,
    int K, int Nn) {
  const int e = blockIdx.z;
  const int cnt = cnts[e];
  const int mt = blockIdx.y;
  if (mt * 128 >= cnt) return;
  const int nt = blockIdx.x;
  const int moff = offs[e];
  const int tid = threadIdx.x;
  const int wv = tid >> 6, ln = tid & 63;
  const int lr = ln & 15, lg = ln >> 4;
  const int wm = wv >> 1, wn = wv & 1;

  __shared__ __align__(16) u16 lds[2][128 * 64];
  u16* lA = lds[0];
  u16* lB = lds[1];

  const u16* Abase = Ag + (size_t)moff * K;
  const u16* Bbase = Bt + (size_t)e * Nn * K + (size_t)nt * 128 * K;

  const int srow = ln >> 3;                       // row-in-chunk 0..7
  const int sk = (((ln & 7) ^ srow)) * 8;         // swizzled source octet offset

  f32x4 acc[4][4];
#pragma unroll
  for (int m = 0; m < 4; ++m)
#pragma unroll
    for (int n = 0; n < 4; ++n) {
      acc[m][n][0] = 0.f; acc[m][n][1] = 0.f; acc[m][n][2] = 0.f; acc[m][n][3] = 0.f;
    }

  const int nk = K / 64;
  for (int kt = 0; kt < nk; ++kt) {
#pragma unroll
    for (int i = 0; i < 4; ++i) {
      int c = wv * 4 + i;
      int ra = mt * 128 + c * 8 + srow;
      ra = ra < cnt ? ra : cnt - 1;  // clamp: padded rows discarded in epilogue
      gload16(Abase + (size_t)ra * K + kt * 64 + sk, lA + c * 512);
      gload16(Bbase + (size_t)(c * 8 + srow) * K + kt * 64 + sk, lB + c * 512);
    }
    __syncthreads();
#pragma unroll
    for (int ko = 0; ko < 2; ++ko) {
      s16x8 af[4], bfr[4];
      const int lsw = lr & 7;
#pragma unroll
      for (int m = 0; m < 4; ++m)
        af[m] = *(const s16x8*)(lA + (wm * 64 + m * 16 + lr) * 64 + ((ko * 4 + lg) ^ lsw) * 8);
#pragma unroll
      for (int n = 0; n < 4; ++n)
        bfr[n] = *(const s16x8*)(lB + (wn * 64 + n * 16 + lr) * 64 + ((ko * 4 + lg) ^ lsw) * 8);
#pragma unroll
      for (int m = 0; m < 4; ++m)
#pragma unroll
        for (int n = 0; n < 4; ++n)
          acc[m][n] = __builtin_amdgcn_mfma_f32_16x16x32_bf16(af[m], bfr[n], acc[m][n], 0, 0, 0);
    }
    __syncthreads();
  }

  // epilogue: bias (+gelu), pack bf16 into LDS tile [128][128], coalesced store
  u16* lT = lds[0];  // 32 KB contiguous
  float bv[4];
#pragma unroll
  for (int n = 0; n < 4; ++n) bv[n] = bias[(size_t)e * Nn + nt * 128 + wn * 64 + n * 16 + lr];
#pragma unroll
  for (int m = 0; m < 4; ++m) {
#pragma unroll
    for (int r = 0; r < 4; ++r) {
      int row = wm * 64 + m * 16 + lg * 4 + r;
#pragma unroll
      for (int n = 0; n < 4; ++n) {
        int col = wn * 64 + n * 16 + lr;
        float v = acc[m][n][r] + bv[n];
        if (PHASE == 1) v = gelu_fast(v);
        lT[row * 128 + col] = f2bf(v);
      }
    }
  }
  __syncthreads();
#pragma unroll
  for (int j = 0; j < 8; ++j) {
    int u = j * 256 + tid;           // uint4 index into 128x128 tile
    int row = u >> 4;                // 8 u16 per uint4 -> 16 uint4 per row
    int colb = (u & 15) * 8;
    int grow = mt * 128 + row;
    if (grow < cnt) {
      uint4 v = ((const uint4*)lT)[u];
      *(uint4*)(outp + (size_t)(moff + grow) * Nn + nt * 128 + colb) = v;
    }
  }
}

// out[tok] = w0 * y[slot0] + w1 * y[slot1]
__global__ void combine_kernel(const u16* __restrict__ y, const int* __restrict__ tok_slot,
                               const float* __restrict__ tok_w, float* __restrict__ out) {
  int gid = blockIdx.x * blockDim.x + threadIdx.x;
  int n = gid >> 8;
  int c4 = (gid & 255) * 4;
  int s0 = tok_slot[n * 2], s1 = tok_slot[n * 2 + 1];
  float w0 = tok_w[n * 2], w1 = tok_w[n * 2 + 1];
  uint2 a = *(const uint2*)(y + (size_t)s0 * CDIM + c4);
  uint2 b = *(const uint2*)(y + (size_t)s1 * CDIM + c4);
  float4 o;
  o.x = w0 * bflo(a.x) + w1 * bflo(b.x);
  o.y = w0 * bfhi(a.x) + w1 * bfhi(b.x);
  o.z = w0 * bflo(a.y) + w1 * bflo(b.y);
  o.w = w0 * bfhi(a.y) + w1 * bfhi(b.y);
  *(float4*)(out + (size_t)n * CDIM + c4) = o;
}

extern "C" void kernel_launch(void* const* d_in, const int* in_sizes, int n_in,
                              void* d_out, int out_size, void* d_ws, size_t ws_size,
                              hipStream_t stream) {
  const float* x  = (const float*)d_in[0];
  const float* wg = (const float*)d_in[1];
  const float* w1 = (const float*)d_in[2];
  const float* b1 = (const float*)d_in[3];
  const float* w2 = (const float*)d_in[4];
  const float* b2 = (const float*)d_in[5];
  float* out = (float*)d_out;

  char* ws = (char*)d_ws;
  int* cnt  = (int*)ws;        // 8 ints
  int* fill = cnt + 8;         // 8 ints
  int* offs = cnt + 16;        // 8 ints
  size_t off = 256;
  int*   tok_e    = (int*)(ws + off);   off += (size_t)NTOK * 2 * 4;
  float* tok_w    = (float*)(ws + off); off += (size_t)NTOK * 2 * 4;
  int*   slot_tok = (int*)(ws + off);   off += (size_t)NTOK * 2 * 4;
  int*   tok_slot = (int*)(ws + off);   off += (size_t)NTOK * 2 * 4;
  u16*   xg  = (u16*)(ws + off); off += (size_t)NTOK * 2 * CDIM * 2;        // 33.5 MB
  u16*   h   = (u16*)(ws + off); off += (size_t)NTOK * 2 * HDIM * 2;        // 134 MB
  u16*   y   = (u16*)(ws + off); off += (size_t)NTOK * 2 * CDIM * 2;        // 33.5 MB
  u16*   w1t = (u16*)(ws + off); off += (size_t)ENUM * CDIM * HDIM * 2;     // 67 MB
  u16*   w2t = (u16*)(ws + off); off += (size_t)ENUM * HDIM * CDIM * 2;     // 67 MB

  hipMemsetAsync(cnt, 0, 64, stream);  // cnt + fill

  wconv_kernel<<<dim3(HDIM / 64, CDIM / 64, ENUM), 256, 0, stream>>>(w1, w1t, CDIM, HDIM);
  wconv_kernel<<<dim3(CDIM / 64, HDIM / 64, ENUM), 256, 0, stream>>>(w2, w2t, HDIM, CDIM);

  gate_kernel<<<NTOK / 4, 256, 0, stream>>>(x, wg, cnt, tok_e, tok_w);
  offsets_kernel<<<1, 64, 0, stream>>>(cnt, offs);
  assign_kernel<<<NTOK / 256, 256, 0, stream>>>(tok_e, offs, fill, slot_tok, tok_slot);
  gather_kernel<<<NTOK * 2, 256, 0, stream>>>(x, slot_tok, xg);

  moe_gemm<1><<<dim3(HDIM / 128, NTOK / 128, ENUM), 256, 0, stream>>>(
      xg, w1t, b1, h, cnt, offs, CDIM, HDIM);
  moe_gemm<2><<<dim3(CDIM / 128, NTOK / 128, ENUM), 256, 0, stream>>>(
      h, w2t, b2, y, cnt, offs, HDIM, CDIM);

  combine_kernel<<<NTOK, 256, 0, stream>>>(y, tok_slot, tok_w, out);
}